// Round 4
// baseline (1911.539 us; speedup 1.0000x reference)
//
#include <hip/hip_runtime.h>
#include <hip/hip_bf16.h>

// ---------------------------------------------------------------------------
// TAGConv (K=2) x2 + segment-max pool + linear head. bf16 intermediates,
// fp32 accumulate. Layer-2 commuted: z2@W2 = X1@W2a + P(X1@W2b + P(X1@W2c)).
// Round 4: windowed multi-pass CSR fill (kills 16x write amplification seen
// in rocprof: WRITE_SIZE 194MB for a 12.8MB colidx), prop edge-unroll x16.
// ---------------------------------------------------------------------------

typedef unsigned short u16;
typedef unsigned int u32;

__device__ inline float u2f(u16 u) { return __uint_as_float(((u32)u) << 16); }
__device__ inline u16 f2u(float f) {
    __hip_bfloat16 b = __float2bfloat16(f);
    return *reinterpret_cast<u16*>(&b);
}

// ---------------------------- CSR build ------------------------------------

__global__ void hist_kernel(const int* __restrict__ dst, int* __restrict__ deg, int E) {
    int i = blockIdx.x * blockDim.x + threadIdx.x;
    if (i < E) atomicAdd(&deg[dst[i]], 1);
}

__global__ void norm_kernel(const int* __restrict__ deg, float* __restrict__ normv, int N) {
    int i = blockIdx.x * blockDim.x + threadIdx.x;
    if (i < N) {
        int d = deg[i];
        float fd = d < 1 ? 1.0f : (float)d;
        normv[i] = rsqrtf(fd);
    }
}

// Multi-block scan: scan1 (per-1024-chunk local excl scan + block sums),
// scan2 (single block excl scan of sums), scan3 (add offsets, write cursor).
__global__ void scan1_kernel(const int* __restrict__ deg, int* __restrict__ rowptr,
                             int* __restrict__ bsum, int n) {
    __shared__ int sd[1024];
    int t = threadIdx.x;
    int i = blockIdx.x * 1024 + t;
    int v = (i < n) ? deg[i] : 0;
    sd[t] = v;
    __syncthreads();
    for (int off = 1; off < 1024; off <<= 1) {
        int x = (t >= off) ? sd[t - off] : 0;
        __syncthreads();
        sd[t] += x;
        __syncthreads();
    }
    if (i < n) rowptr[i] = sd[t] - v;
    if (t == 1023) bsum[blockIdx.x] = sd[t];
}

__global__ void scan2_kernel(int* __restrict__ bsum, int nb) {
    __shared__ int sd[1024];
    int t = threadIdx.x;
    int v = (t < nb) ? bsum[t] : 0;
    sd[t] = v;
    __syncthreads();
    for (int off = 1; off < 1024; off <<= 1) {
        int x = (t >= off) ? sd[t - off] : 0;
        __syncthreads();
        sd[t] += x;
        __syncthreads();
    }
    if (t < nb) bsum[t] = sd[t] - v;
}

__global__ void scan3_kernel(int* __restrict__ rowptr, int* __restrict__ cursor,
                             const int* __restrict__ bsum, int n, int E) {
    int i = blockIdx.x * blockDim.x + threadIdx.x;
    if (i < n) {
        int r = rowptr[i] + bsum[i >> 10];
        rowptr[i] = r;
        cursor[i] = r;
    }
    if (i == 0) rowptr[n] = E;
}

// Windowed fill: only edges with dst in [lo, hi) are scattered this pass.
// Keeps the colidx write window ~2MB -> L2-resident, single writeback.
__global__ void fill_kernel(const int* __restrict__ src, const int* __restrict__ dst,
                            int* __restrict__ cursor, int* __restrict__ colidx,
                            int E, int lo, int hi) {
    int i = blockIdx.x * blockDim.x + threadIdx.x;
    if (i < E) {
        int d = dst[i];
        if (d >= lo && d < hi) {
            int pos = atomicAdd(&cursor[d], 1);
            colidx[pos] = src[i];
        }
    }
}

// ------------------------------ cast h -------------------------------------

struct alignas(4) U2 { u16 v[2]; };
struct alignas(8) U4 { u16 v[4]; };
template <int VPT> struct VT;
template <> struct VT<2> { using T = U2; };
template <> struct VT<4> { using T = U4; };

// CAT1[:, 0:IN] = bf16(h), 4 floats per thread
__global__ void cast_kernel(const float* __restrict__ h, u16* __restrict__ cat,
                            int ngroups, int in4, int ldcat) {
    int i = blockIdx.x * blockDim.x + threadIdx.x;
    if (i < ngroups) {
        int r = i / in4, c4 = i % in4;
        float4 f = *(const float4*)(h + (size_t)i * 4);
        U4 o;
        o.v[0] = f2u(f.x); o.v[1] = f2u(f.y); o.v[2] = f2u(f.z); o.v[3] = f2u(f.w);
        *(U4*)(cat + (size_t)r * ldcat + c4 * 4) = o;
    }
}

// ----------------------------- propagation ---------------------------------
// out[i,:] = norm[i] * sum_{e in row i} norm[col_e] * in[col_e,:]
// One wave per node (4 nodes/block). Lane holds VPT features (vector load).
// Edge loop unrolled x16 for memory-level parallelism.

template <int VPT>
__global__ __launch_bounds__(256) void prop_kernel(
    const u16* __restrict__ in, int ldin,
    u16* __restrict__ out, int ldout,
    const int* __restrict__ rowptr, const int* __restrict__ colidx,
    const float* __restrict__ normv, int N) {
    using V = typename VT<VPT>::T;
    int node = blockIdx.x * 4 + (threadIdx.x >> 6);
    if (node >= N) return;
    int lane = threadIdx.x & 63;
    const u16* ip = in + lane * VPT;
    int s = rowptr[node], e = rowptr[node + 1];
    float acc[VPT];
    #pragma unroll
    for (int q = 0; q < VPT; ++q) acc[q] = 0.f;
    int p = s;
    for (; p + 16 <= e; p += 16) {
        int c[16];
        #pragma unroll
        for (int j = 0; j < 16; ++j) c[j] = colidx[p + j];
        V v[16];
        #pragma unroll
        for (int j = 0; j < 16; ++j) v[j] = *(const V*)(ip + (size_t)c[j] * ldin);
        float nm[16];
        #pragma unroll
        for (int j = 0; j < 16; ++j) nm[j] = normv[c[j]];
        #pragma unroll
        for (int j = 0; j < 16; ++j)
            #pragma unroll
            for (int q = 0; q < VPT; ++q)
                acc[q] += nm[j] * u2f(v[j].v[q]);
    }
    for (; p < e; ++p) {
        int c = colidx[p];
        float nm = normv[c];
        V v = *(const V*)(ip + (size_t)c * ldin);
        #pragma unroll
        for (int q = 0; q < VPT; ++q) acc[q] += nm * u2f(v.v[q]);
    }
    float nn = normv[node];
    V o;
    #pragma unroll
    for (int q = 0; q < VPT; ++q) o.v[q] = f2u(nn * acc[q]);
    *(V*)(out + (size_t)node * ldout + lane * VPT) = o;
}

// ------------------------------- MFMA GEMM ---------------------------------
// Cout[M x 256] = [relu]( A(bf16,[Mpad x lda]) @ Bt^T [+Cadd] [+bias] ) -> bf16
// Bt is [256 x K] bf16 row-major (pre-transposed weights, k-contiguous).
// Tile 128x64, BK=32, 4 waves (2x2), wave = 4x2 grid of 16x16x32 MFMAs.
// B panel (64 x K <= 48 KB) resident in LDS; A tile double-buffered via
// global_load_lds width-16.

typedef __attribute__((ext_vector_type(8))) short bf16x8f;
typedef __attribute__((ext_vector_type(4))) float f32x4;

__device__ inline void async16(const void* g, void* l) {
    __builtin_amdgcn_global_load_lds(
        (__attribute__((address_space(1))) void*)(g),
        (__attribute__((address_space(3))) void*)(l), 16, 0, 0);
}

constexpr int GBM = 128, GBN = 64, GBK = 32, KMAX = 384;

__device__ inline void stageA(const u16* __restrict__ A, int lda, int row0, int k0,
                              u16* dst, int tid) {
    // 128 rows x 32 bf16 cols = 8 KB = 512 x 16B chunks; 256 threads x 2.
    #pragma unroll
    for (int i = 0; i < 2; ++i) {
        int c = tid + i * 256;
        int row = c >> 2, seg = c & 3;
        async16(A + (size_t)(row0 + row) * lda + k0 + seg * 8, dst + c * 8);
    }
}

__global__ __launch_bounds__(256) void gemm_mfma(
    const u16* __restrict__ A, int lda,
    const u16* __restrict__ Bt,          // [256 x K]
    const u16* __restrict__ Cadd,        // nullable, [Mpad x 256]
    const float* __restrict__ bias,      // nullable, [256]
    u16* __restrict__ Cout,              // [Mpad x 256]
    int M, int K, int relu) {
    __shared__ u16 Ab[2][GBM * GBK];
    __shared__ u16 Bs[GBN * KMAX];
    const int tid = threadIdx.x;
    const int lane = tid & 63;
    const int wave = tid >> 6;
    const int wm = wave >> 1, wn = wave & 1;
    const int row0 = blockIdx.x * GBM;
    const int col0 = blockIdx.y * GBN;
    const int NOUT = 256;

    // stage B panel: contiguous 64*K bf16 from Bt + col0*K
    {
        const u16* src = Bt + (size_t)col0 * K;
        int chunks = GBN * K / 8;
        for (int c = tid; c < chunks; c += 256) async16(src + c * 8, &Bs[c * 8]);
    }
    stageA(A, lda, row0, 0, Ab[0], tid);
    __syncthreads();

    f32x4 acc[4][2];
    #pragma unroll
    for (int mi = 0; mi < 4; ++mi)
        #pragma unroll
        for (int ni = 0; ni < 2; ++ni) acc[mi][ni] = (f32x4)0.f;

    const int nk = K / GBK;
    const int mb = lane & 15;
    const int kk = (lane >> 4) * 8;
    for (int ks = 0; ks < nk; ++ks) {
        int cur = ks & 1;
        if (ks + 1 < nk) stageA(A, lda, row0, (ks + 1) * GBK, Ab[cur ^ 1], tid);
        bf16x8f a[4], b[2];
        #pragma unroll
        for (int mi = 0; mi < 4; ++mi)
            a[mi] = *(const bf16x8f*)&Ab[cur][(wm * 64 + mi * 16 + mb) * GBK + kk];
        #pragma unroll
        for (int ni = 0; ni < 2; ++ni)
            b[ni] = *(const bf16x8f*)&Bs[(size_t)(wn * 32 + ni * 16 + mb) * K + ks * GBK + kk];
        #pragma unroll
        for (int mi = 0; mi < 4; ++mi)
            #pragma unroll
            for (int ni = 0; ni < 2; ++ni)
                acc[mi][ni] = __builtin_amdgcn_mfma_f32_16x16x32_bf16(
                    a[mi], b[ni], acc[mi][ni], 0, 0, 0);
        __syncthreads();
    }

    // epilogue: C/D layout col = lane&15, row = (lane>>4)*4 + r
    #pragma unroll
    for (int mi = 0; mi < 4; ++mi) {
        #pragma unroll
        for (int r = 0; r < 4; ++r) {
            int row = row0 + wm * 64 + mi * 16 + (lane >> 4) * 4 + r;
            if (row < M) {
                #pragma unroll
                for (int ni = 0; ni < 2; ++ni) {
                    int col = col0 + wn * 32 + ni * 16 + (lane & 15);
                    float v = acc[mi][ni][r];
                    if (Cadd) v += u2f(Cadd[(size_t)row * NOUT + col]);
                    if (bias) v += bias[col];
                    if (relu) v = fmaxf(v, 0.f);
                    Cout[(size_t)row * NOUT + col] = f2u(v);
                }
            }
        }
    }
}

// Wt[n*K + k] = bf16(W[k*Nn + n])
__global__ void transpose_cast(const float* __restrict__ W, u16* __restrict__ Wt,
                               int K, int Nn) {
    int idx = blockIdx.x * blockDim.x + threadIdx.x;
    if (idx < K * Nn) {
        int n = idx / K, k = idx % K;
        Wt[idx] = f2u(W[(size_t)k * Nn + n]);
    }
}

// ------------------------------ pool + head --------------------------------

__global__ void pool_kernel(const u16* __restrict__ x, const int* __restrict__ gid,
                            float* __restrict__ pooled, int N, int HID) {
    int t = threadIdx.x;
    int n0 = blockIdx.x * 128;
    int n1 = n0 + 128 < N ? n0 + 128 : N;
    float cur = 0.f;
    int cg = gid[n0];
    for (int n = n0; n < n1; ++n) {
        int g = gid[n];
        if (g != cg) {
            atomicMax((int*)&pooled[(size_t)cg * HID + t], __float_as_int(cur));
            cg = g;
            cur = 0.f;
        }
        float v = u2f(x[(size_t)n * HID + t]);
        cur = cur > v ? cur : v;
    }
    atomicMax((int*)&pooled[(size_t)cg * HID + t], __float_as_int(cur));
}

__global__ void head_kernel(const float* __restrict__ pooled, const float* __restrict__ Wc,
                            const float* __restrict__ bc, float* __restrict__ out,
                            int HID, int C) {
    __shared__ float row[256];
    int g = blockIdx.x;
    int t = threadIdx.x;
    if (t < HID) row[t] = pooled[(size_t)g * HID + t];
    __syncthreads();
    if (t < C) {
        float s = bc[t];
        for (int k = 0; k < HID; ++k) s += row[k] * Wc[(size_t)k * C + t];
        out[(size_t)g * C + t] = s;
    }
}

// ------------------------------- launch ------------------------------------

extern "C" void kernel_launch(void* const* d_in, const int* in_sizes, int n_in,
                              void* d_out, int out_size, void* d_ws, size_t ws_size,
                              hipStream_t stream) {
    const float* h  = (const float*)d_in[0];
    const int* src  = (const int*)d_in[1];
    const int* dst  = (const int*)d_in[2];
    const int* gid  = (const int*)d_in[3];
    const float* W1 = (const float*)d_in[4];
    const float* b1 = (const float*)d_in[5];
    const float* W2 = (const float*)d_in[6];
    const float* b2 = (const float*)d_in[7];
    const float* Wc = (const float*)d_in[8];
    const float* bc = (const float*)d_in[9];
    float* out = (float*)d_out;

    const int N   = in_sizes[3];          // 100000
    const int E   = in_sizes[1];          // 3200000
    const int IN  = in_sizes[0] / N;      // 128
    const int HID = in_sizes[5];          // 256
    const int C   = in_sizes[9];          // 10
    const int G   = out_size / C;         // 64
    const int CAT = 3 * IN;               // 384
    const int Mpad = (N + 127) & ~127;    // 100096 (multiple of GBM)

    char* wp = (char*)d_ws;
    auto alloc = [&](size_t bytes) {
        char* p = wp;
        wp += (bytes + 255) & ~(size_t)255;
        return p;
    };
    float* pooled = (float*)alloc((size_t)G * HID * sizeof(float));
    float* normv  = (float*)alloc((size_t)N * sizeof(float));
    int* deg      = (int*)alloc((size_t)N * sizeof(int));
    int* rowptr   = (int*)alloc((size_t)(N + 1) * sizeof(int));
    int* cursor   = (int*)alloc((size_t)N * sizeof(int));
    int* bsum     = (int*)alloc(1024 * sizeof(int));
    int* colidx   = (int*)alloc((size_t)E * sizeof(int));
    u16* Wt1      = (u16*)alloc((size_t)CAT * HID * sizeof(u16));        // [256 x 384]
    u16* Wt2      = (u16*)alloc((size_t)3 * HID * HID * sizeof(u16));    // 3 x [256 x 256]
    u16* CAT1     = (u16*)alloc((size_t)Mpad * CAT * sizeof(u16));       // [h|Ph|P2h]
    u16* X1       = (u16*)alloc((size_t)Mpad * HID * sizeof(u16));
    u16* B2       = (u16*)alloc((size_t)Mpad * HID * sizeof(u16));
    u16* B1       = CAT1;   // alias: CAT1 dead after GEMM1

    // --- norm + CSR build ---
    hipMemsetAsync(deg, 0, (size_t)N * sizeof(int), stream);
    hist_kernel<<<(E + 255) / 256, 256, 0, stream>>>(dst, deg, E);
    norm_kernel<<<(N + 255) / 256, 256, 0, stream>>>(deg, normv, N);
    int nb = (N + 1023) / 1024;
    scan1_kernel<<<nb, 1024, 0, stream>>>(deg, rowptr, bsum, N);
    scan2_kernel<<<1, 1024, 0, stream>>>(bsum, nb);
    scan3_kernel<<<(N + 255) / 256, 256, 0, stream>>>(rowptr, cursor, bsum, N, E);
    // windowed passes: colidx write window ~E/6*4B ~ 2.1MB -> L2-resident
    {
        const int P = 6;
        int step = (N + P - 1) / P;
        for (int p = 0; p < P; ++p) {
            int lo = p * step;
            int hi = lo + step < N ? lo + step : N;
            if (lo >= hi) break;
            fill_kernel<<<(E + 255) / 256, 256, 0, stream>>>(src, dst, cursor, colidx,
                                                             E, lo, hi);
        }
    }

    // --- weight transpose + bf16 cast (small) ---
    transpose_cast<<<(CAT * HID + 255) / 256, 256, 0, stream>>>(W1, Wt1, CAT, HID);
    for (int s2 = 0; s2 < 3; ++s2)
        transpose_cast<<<(HID * HID + 255) / 256, 256, 0, stream>>>(
            W2 + (size_t)s2 * HID * HID, Wt2 + (size_t)s2 * HID * HID, HID, HID);

    // --- layer 1: CAT1 = [bf16(h) | P h | P^2 h]; X1 = relu(CAT1@W1+b1) ---
    {
        int ngroups = N * (IN / 4);
        cast_kernel<<<(ngroups + 255) / 256, 256, 0, stream>>>(h, CAT1, ngroups, IN / 4, CAT);
    }
    prop_kernel<2><<<(N + 3) / 4, 256, 0, stream>>>(CAT1, CAT, CAT1 + IN, CAT,
                                                    rowptr, colidx, normv, N);
    prop_kernel<2><<<(N + 3) / 4, 256, 0, stream>>>(CAT1 + IN, CAT, CAT1 + 2 * IN, CAT,
                                                    rowptr, colidx, normv, N);
    dim3 ggrid(Mpad / GBM, HID / GBN);
    gemm_mfma<<<ggrid, 256, 0, stream>>>(CAT1, CAT, Wt1, nullptr, b1, X1, N, CAT, 1);

    // --- layer 2 (commuted): X2 = relu(X1@W2a + P(X1@W2b + P(X1@W2c)) + b2) ---
    gemm_mfma<<<ggrid, 256, 0, stream>>>(X1, HID, Wt2 + (size_t)2 * HID * HID,
                                         nullptr, nullptr, B1, N, HID, 0);
    prop_kernel<4><<<(N + 3) / 4, 256, 0, stream>>>(B1, HID, B2, HID,
                                                    rowptr, colidx, normv, N);
    gemm_mfma<<<ggrid, 256, 0, stream>>>(X1, HID, Wt2 + (size_t)HID * HID,
                                         B2, nullptr, B1, N, HID, 0);
    prop_kernel<4><<<(N + 3) / 4, 256, 0, stream>>>(B1, HID, B2, HID,
                                                    rowptr, colidx, normv, N);
    gemm_mfma<<<ggrid, 256, 0, stream>>>(X1, HID, Wt2, B2, b2, B1, N, HID, 1);

    // --- pool + head ---
    hipMemsetAsync(pooled, 0, (size_t)G * HID * sizeof(float), stream);
    pool_kernel<<<(N + 127) / 128, HID, 0, stream>>>(B1, gid, pooled, N, HID);
    head_kernel<<<G, HID, 0, stream>>>(pooled, Wc, bc, out, HID, C);
}

// Round 5
// 1533.216 us; speedup vs baseline: 1.2468x; 1.2468x over previous
//
#include <hip/hip_runtime.h>
#include <hip/hip_bf16.h>

// ---------------------------------------------------------------------------
// TAGConv (K=2) x2 + segment-max pool + linear head. bf16 intermediates,
// fp32 accumulate. Layer-2 commuted: z2@W2 = X1@W2a + P(X1@W2b + P(X1@W2c)).
// Round 5: XCD-ownership-partitioned hist/fill (blockIdx&7 -> dst window, so
// scattered lines are dirtied by ONE XCD's L2 only -> single writeback; fixes
// the 194MB cross-XCD false-sharing writeback seen in rocprof). Prop back to
// unroll x8 (x16 was neutral, latency-bound with enough MLP).
// ---------------------------------------------------------------------------

typedef unsigned short u16;
typedef unsigned int u32;

__device__ inline float u2f(u16 u) { return __uint_as_float(((u32)u) << 16); }
__device__ inline u16 f2u(float f) {
    __hip_bfloat16 b = __float2bfloat16(f);
    return *reinterpret_cast<u16*>(&b);
}

// ---------------------------- CSR build ------------------------------------
// hist/fill: 8 dst-windows; group w = blockIdx&7 owns window w and scans the
// whole edge list (grid-stride). Under round-robin block->XCD dispatch all
// stores to a window come from one XCD => L2-resident, one writeback.

__global__ __launch_bounds__(256) void hist_kernel(
    const int* __restrict__ dst, int* __restrict__ deg, int E, int wstep) {
    int grp = blockIdx.x & 7;
    int vb  = blockIdx.x >> 3;
    int nvb = gridDim.x >> 3;
    int lo = grp * wstep, hi = lo + wstep;
    int stride = nvb * 256;
    for (int i = vb * 256 + threadIdx.x; i < E; i += stride) {
        int d = dst[i];
        if (d >= lo && d < hi) atomicAdd(&deg[d], 1);
    }
}

__global__ __launch_bounds__(256) void fill_kernel(
    const int* __restrict__ src, const int* __restrict__ dst,
    int* __restrict__ cursor, int* __restrict__ colidx, int E, int wstep) {
    int grp = blockIdx.x & 7;
    int vb  = blockIdx.x >> 3;
    int nvb = gridDim.x >> 3;
    int lo = grp * wstep, hi = lo + wstep;
    int stride = nvb * 256;
    for (int i = vb * 256 + threadIdx.x; i < E; i += stride) {
        int d = dst[i];
        if (d >= lo && d < hi) {
            int pos = atomicAdd(&cursor[d], 1);
            colidx[pos] = src[i];
        }
    }
}

__global__ void norm_kernel(const int* __restrict__ deg, float* __restrict__ normv, int N) {
    int i = blockIdx.x * blockDim.x + threadIdx.x;
    if (i < N) {
        int d = deg[i];
        float fd = d < 1 ? 1.0f : (float)d;
        normv[i] = rsqrtf(fd);
    }
}

// Multi-block scan: scan1 (per-1024-chunk local excl scan + block sums),
// scan2 (single block excl scan of sums), scan3 (add offsets, write cursor).
__global__ void scan1_kernel(const int* __restrict__ deg, int* __restrict__ rowptr,
                             int* __restrict__ bsum, int n) {
    __shared__ int sd[1024];
    int t = threadIdx.x;
    int i = blockIdx.x * 1024 + t;
    int v = (i < n) ? deg[i] : 0;
    sd[t] = v;
    __syncthreads();
    for (int off = 1; off < 1024; off <<= 1) {
        int x = (t >= off) ? sd[t - off] : 0;
        __syncthreads();
        sd[t] += x;
        __syncthreads();
    }
    if (i < n) rowptr[i] = sd[t] - v;
    if (t == 1023) bsum[blockIdx.x] = sd[t];
}

__global__ void scan2_kernel(int* __restrict__ bsum, int nb) {
    __shared__ int sd[1024];
    int t = threadIdx.x;
    int v = (t < nb) ? bsum[t] : 0;
    sd[t] = v;
    __syncthreads();
    for (int off = 1; off < 1024; off <<= 1) {
        int x = (t >= off) ? sd[t - off] : 0;
        __syncthreads();
        sd[t] += x;
        __syncthreads();
    }
    if (t < nb) bsum[t] = sd[t] - v;
}

__global__ void scan3_kernel(int* __restrict__ rowptr, int* __restrict__ cursor,
                             const int* __restrict__ bsum, int n, int E) {
    int i = blockIdx.x * blockDim.x + threadIdx.x;
    if (i < n) {
        int r = rowptr[i] + bsum[i >> 10];
        rowptr[i] = r;
        cursor[i] = r;
    }
    if (i == 0) rowptr[n] = E;
}

// ------------------------------ cast h -------------------------------------

struct alignas(4) U2 { u16 v[2]; };
struct alignas(8) U4 { u16 v[4]; };
template <int VPT> struct VT;
template <> struct VT<2> { using T = U2; };
template <> struct VT<4> { using T = U4; };

// CAT1[:, 0:IN] = bf16(h), 4 floats per thread
__global__ void cast_kernel(const float* __restrict__ h, u16* __restrict__ cat,
                            int ngroups, int in4, int ldcat) {
    int i = blockIdx.x * blockDim.x + threadIdx.x;
    if (i < ngroups) {
        int r = i / in4, c4 = i % in4;
        float4 f = *(const float4*)(h + (size_t)i * 4);
        U4 o;
        o.v[0] = f2u(f.x); o.v[1] = f2u(f.y); o.v[2] = f2u(f.z); o.v[3] = f2u(f.w);
        *(U4*)(cat + (size_t)r * ldcat + c4 * 4) = o;
    }
}

// ----------------------------- propagation ---------------------------------
// out[i,:] = norm[i] * sum_{e in row i} norm[col_e] * in[col_e,:]
// One wave per node (4 nodes/block). Lane holds VPT features (vector load).
// Edge loop unrolled x8 for memory-level parallelism.

template <int VPT>
__global__ __launch_bounds__(256) void prop_kernel(
    const u16* __restrict__ in, int ldin,
    u16* __restrict__ out, int ldout,
    const int* __restrict__ rowptr, const int* __restrict__ colidx,
    const float* __restrict__ normv, int N) {
    using V = typename VT<VPT>::T;
    int node = blockIdx.x * 4 + (threadIdx.x >> 6);
    if (node >= N) return;
    int lane = threadIdx.x & 63;
    const u16* ip = in + lane * VPT;
    int s = rowptr[node], e = rowptr[node + 1];
    float acc[VPT];
    #pragma unroll
    for (int q = 0; q < VPT; ++q) acc[q] = 0.f;
    int p = s;
    for (; p + 8 <= e; p += 8) {
        int c[8];
        #pragma unroll
        for (int j = 0; j < 8; ++j) c[j] = colidx[p + j];
        V v[8];
        #pragma unroll
        for (int j = 0; j < 8; ++j) v[j] = *(const V*)(ip + (size_t)c[j] * ldin);
        float nm[8];
        #pragma unroll
        for (int j = 0; j < 8; ++j) nm[j] = normv[c[j]];
        #pragma unroll
        for (int j = 0; j < 8; ++j)
            #pragma unroll
            for (int q = 0; q < VPT; ++q)
                acc[q] += nm[j] * u2f(v[j].v[q]);
    }
    for (; p < e; ++p) {
        int c = colidx[p];
        float nm = normv[c];
        V v = *(const V*)(ip + (size_t)c * ldin);
        #pragma unroll
        for (int q = 0; q < VPT; ++q) acc[q] += nm * u2f(v.v[q]);
    }
    float nn = normv[node];
    V o;
    #pragma unroll
    for (int q = 0; q < VPT; ++q) o.v[q] = f2u(nn * acc[q]);
    *(V*)(out + (size_t)node * ldout + lane * VPT) = o;
}

// ------------------------------- MFMA GEMM ---------------------------------
// Cout[M x 256] = [relu]( A(bf16,[Mpad x lda]) @ Bt^T [+Cadd] [+bias] ) -> bf16
// Bt is [256 x K] bf16 row-major (pre-transposed weights, k-contiguous).
// Tile 128x64, BK=32, 4 waves (2x2), wave = 4x2 grid of 16x16x32 MFMAs.
// B panel (64 x K <= 48 KB) resident in LDS; A tile double-buffered via
// global_load_lds width-16.

typedef __attribute__((ext_vector_type(8))) short bf16x8f;
typedef __attribute__((ext_vector_type(4))) float f32x4;

__device__ inline void async16(const void* g, void* l) {
    __builtin_amdgcn_global_load_lds(
        (__attribute__((address_space(1))) void*)(g),
        (__attribute__((address_space(3))) void*)(l), 16, 0, 0);
}

constexpr int GBM = 128, GBN = 64, GBK = 32, KMAX = 384;

__device__ inline void stageA(const u16* __restrict__ A, int lda, int row0, int k0,
                              u16* dst, int tid) {
    // 128 rows x 32 bf16 cols = 8 KB = 512 x 16B chunks; 256 threads x 2.
    #pragma unroll
    for (int i = 0; i < 2; ++i) {
        int c = tid + i * 256;
        int row = c >> 2, seg = c & 3;
        async16(A + (size_t)(row0 + row) * lda + k0 + seg * 8, dst + c * 8);
    }
}

__global__ __launch_bounds__(256) void gemm_mfma(
    const u16* __restrict__ A, int lda,
    const u16* __restrict__ Bt,          // [256 x K]
    const u16* __restrict__ Cadd,        // nullable, [Mpad x 256]
    const float* __restrict__ bias,      // nullable, [256]
    u16* __restrict__ Cout,              // [Mpad x 256]
    int M, int K, int relu) {
    __shared__ u16 Ab[2][GBM * GBK];
    __shared__ u16 Bs[GBN * KMAX];
    const int tid = threadIdx.x;
    const int lane = tid & 63;
    const int wave = tid >> 6;
    const int wm = wave >> 1, wn = wave & 1;
    const int row0 = blockIdx.x * GBM;
    const int col0 = blockIdx.y * GBN;
    const int NOUT = 256;

    // stage B panel: contiguous 64*K bf16 from Bt + col0*K
    {
        const u16* src = Bt + (size_t)col0 * K;
        int chunks = GBN * K / 8;
        for (int c = tid; c < chunks; c += 256) async16(src + c * 8, &Bs[c * 8]);
    }
    stageA(A, lda, row0, 0, Ab[0], tid);
    __syncthreads();

    f32x4 acc[4][2];
    #pragma unroll
    for (int mi = 0; mi < 4; ++mi)
        #pragma unroll
        for (int ni = 0; ni < 2; ++ni) acc[mi][ni] = (f32x4)0.f;

    const int nk = K / GBK;
    const int mb = lane & 15;
    const int kk = (lane >> 4) * 8;
    for (int ks = 0; ks < nk; ++ks) {
        int cur = ks & 1;
        if (ks + 1 < nk) stageA(A, lda, row0, (ks + 1) * GBK, Ab[cur ^ 1], tid);
        bf16x8f a[4], b[2];
        #pragma unroll
        for (int mi = 0; mi < 4; ++mi)
            a[mi] = *(const bf16x8f*)&Ab[cur][(wm * 64 + mi * 16 + mb) * GBK + kk];
        #pragma unroll
        for (int ni = 0; ni < 2; ++ni)
            b[ni] = *(const bf16x8f*)&Bs[(size_t)(wn * 32 + ni * 16 + mb) * K + ks * GBK + kk];
        #pragma unroll
        for (int mi = 0; mi < 4; ++mi)
            #pragma unroll
            for (int ni = 0; ni < 2; ++ni)
                acc[mi][ni] = __builtin_amdgcn_mfma_f32_16x16x32_bf16(
                    a[mi], b[ni], acc[mi][ni], 0, 0, 0);
        __syncthreads();
    }

    // epilogue: C/D layout col = lane&15, row = (lane>>4)*4 + r
    #pragma unroll
    for (int mi = 0; mi < 4; ++mi) {
        #pragma unroll
        for (int r = 0; r < 4; ++r) {
            int row = row0 + wm * 64 + mi * 16 + (lane >> 4) * 4 + r;
            if (row < M) {
                #pragma unroll
                for (int ni = 0; ni < 2; ++ni) {
                    int col = col0 + wn * 32 + ni * 16 + (lane & 15);
                    float v = acc[mi][ni][r];
                    if (Cadd) v += u2f(Cadd[(size_t)row * NOUT + col]);
                    if (bias) v += bias[col];
                    if (relu) v = fmaxf(v, 0.f);
                    Cout[(size_t)row * NOUT + col] = f2u(v);
                }
            }
        }
    }
}

// Wt[n*K + k] = bf16(W[k*Nn + n])
__global__ void transpose_cast(const float* __restrict__ W, u16* __restrict__ Wt,
                               int K, int Nn) {
    int idx = blockIdx.x * blockDim.x + threadIdx.x;
    if (idx < K * Nn) {
        int n = idx / K, k = idx % K;
        Wt[idx] = f2u(W[(size_t)k * Nn + n]);
    }
}

// ------------------------------ pool + head --------------------------------

__global__ void pool_kernel(const u16* __restrict__ x, const int* __restrict__ gid,
                            float* __restrict__ pooled, int N, int HID) {
    int t = threadIdx.x;
    int n0 = blockIdx.x * 128;
    int n1 = n0 + 128 < N ? n0 + 128 : N;
    float cur = 0.f;
    int cg = gid[n0];
    for (int n = n0; n < n1; ++n) {
        int g = gid[n];
        if (g != cg) {
            atomicMax((int*)&pooled[(size_t)cg * HID + t], __float_as_int(cur));
            cg = g;
            cur = 0.f;
        }
        float v = u2f(x[(size_t)n * HID + t]);
        cur = cur > v ? cur : v;
    }
    atomicMax((int*)&pooled[(size_t)cg * HID + t], __float_as_int(cur));
}

__global__ void head_kernel(const float* __restrict__ pooled, const float* __restrict__ Wc,
                            const float* __restrict__ bc, float* __restrict__ out,
                            int HID, int C) {
    __shared__ float row[256];
    int g = blockIdx.x;
    int t = threadIdx.x;
    if (t < HID) row[t] = pooled[(size_t)g * HID + t];
    __syncthreads();
    if (t < C) {
        float s = bc[t];
        for (int k = 0; k < HID; ++k) s += row[k] * Wc[(size_t)k * C + t];
        out[(size_t)g * C + t] = s;
    }
}

// ------------------------------- launch ------------------------------------

extern "C" void kernel_launch(void* const* d_in, const int* in_sizes, int n_in,
                              void* d_out, int out_size, void* d_ws, size_t ws_size,
                              hipStream_t stream) {
    const float* h  = (const float*)d_in[0];
    const int* src  = (const int*)d_in[1];
    const int* dst  = (const int*)d_in[2];
    const int* gid  = (const int*)d_in[3];
    const float* W1 = (const float*)d_in[4];
    const float* b1 = (const float*)d_in[5];
    const float* W2 = (const float*)d_in[6];
    const float* b2 = (const float*)d_in[7];
    const float* Wc = (const float*)d_in[8];
    const float* bc = (const float*)d_in[9];
    float* out = (float*)d_out;

    const int N   = in_sizes[3];          // 100000
    const int E   = in_sizes[1];          // 3200000
    const int IN  = in_sizes[0] / N;      // 128
    const int HID = in_sizes[5];          // 256
    const int C   = in_sizes[9];          // 10
    const int G   = out_size / C;         // 64
    const int CAT = 3 * IN;               // 384
    const int Mpad = (N + 127) & ~127;    // 100096 (multiple of GBM)

    char* wp = (char*)d_ws;
    auto alloc = [&](size_t bytes) {
        char* p = wp;
        wp += (bytes + 255) & ~(size_t)255;
        return p;
    };
    float* pooled = (float*)alloc((size_t)G * HID * sizeof(float));
    float* normv  = (float*)alloc((size_t)N * sizeof(float));
    int* deg      = (int*)alloc((size_t)N * sizeof(int));
    int* rowptr   = (int*)alloc((size_t)(N + 1) * sizeof(int));
    int* cursor   = (int*)alloc((size_t)N * sizeof(int));
    int* bsum     = (int*)alloc(1024 * sizeof(int));
    int* colidx   = (int*)alloc((size_t)E * sizeof(int));
    u16* Wt1      = (u16*)alloc((size_t)CAT * HID * sizeof(u16));        // [256 x 384]
    u16* Wt2      = (u16*)alloc((size_t)3 * HID * HID * sizeof(u16));    // 3 x [256 x 256]
    u16* CAT1     = (u16*)alloc((size_t)Mpad * CAT * sizeof(u16));       // [h|Ph|P2h]
    u16* X1       = (u16*)alloc((size_t)Mpad * HID * sizeof(u16));
    u16* B2       = (u16*)alloc((size_t)Mpad * HID * sizeof(u16));
    u16* B1       = CAT1;   // alias: CAT1 dead after GEMM1

    // --- norm + CSR build (XCD-ownership windows: 8 windows over dst) ---
    const int wstep = (N + 7) / 8;        // 12500
    hipMemsetAsync(deg, 0, (size_t)N * sizeof(int), stream);
    hist_kernel<<<8 * 512, 256, 0, stream>>>(dst, deg, E, wstep);
    norm_kernel<<<(N + 255) / 256, 256, 0, stream>>>(deg, normv, N);
    int nb = (N + 1023) / 1024;
    scan1_kernel<<<nb, 1024, 0, stream>>>(deg, rowptr, bsum, N);
    scan2_kernel<<<1, 1024, 0, stream>>>(bsum, nb);
    scan3_kernel<<<(N + 255) / 256, 256, 0, stream>>>(rowptr, cursor, bsum, N, E);
    fill_kernel<<<8 * 512, 256, 0, stream>>>(src, dst, cursor, colidx, E, wstep);

    // --- weight transpose + bf16 cast (small) ---
    transpose_cast<<<(CAT * HID + 255) / 256, 256, 0, stream>>>(W1, Wt1, CAT, HID);
    for (int s2 = 0; s2 < 3; ++s2)
        transpose_cast<<<(HID * HID + 255) / 256, 256, 0, stream>>>(
            W2 + (size_t)s2 * HID * HID, Wt2 + (size_t)s2 * HID * HID, HID, HID);

    // --- layer 1: CAT1 = [bf16(h) | P h | P^2 h]; X1 = relu(CAT1@W1+b1) ---
    {
        int ngroups = N * (IN / 4);
        cast_kernel<<<(ngroups + 255) / 256, 256, 0, stream>>>(h, CAT1, ngroups, IN / 4, CAT);
    }
    prop_kernel<2><<<(N + 3) / 4, 256, 0, stream>>>(CAT1, CAT, CAT1 + IN, CAT,
                                                    rowptr, colidx, normv, N);
    prop_kernel<2><<<(N + 3) / 4, 256, 0, stream>>>(CAT1 + IN, CAT, CAT1 + 2 * IN, CAT,
                                                    rowptr, colidx, normv, N);
    dim3 ggrid(Mpad / GBM, HID / GBN);
    gemm_mfma<<<ggrid, 256, 0, stream>>>(CAT1, CAT, Wt1, nullptr, b1, X1, N, CAT, 1);

    // --- layer 2 (commuted): X2 = relu(X1@W2a + P(X1@W2b + P(X1@W2c)) + b2) ---
    gemm_mfma<<<ggrid, 256, 0, stream>>>(X1, HID, Wt2 + (size_t)2 * HID * HID,
                                         nullptr, nullptr, B1, N, HID, 0);
    prop_kernel<4><<<(N + 3) / 4, 256, 0, stream>>>(B1, HID, B2, HID,
                                                    rowptr, colidx, normv, N);
    gemm_mfma<<<ggrid, 256, 0, stream>>>(X1, HID, Wt2 + (size_t)HID * HID,
                                         B2, nullptr, B1, N, HID, 0);
    prop_kernel<4><<<(N + 3) / 4, 256, 0, stream>>>(B1, HID, B2, HID,
                                                    rowptr, colidx, normv, N);
    gemm_mfma<<<ggrid, 256, 0, stream>>>(X1, HID, Wt2, B2, b2, B1, N, HID, 1);

    // --- pool + head ---
    hipMemsetAsync(pooled, 0, (size_t)G * HID * sizeof(float), stream);
    pool_kernel<<<(N + 127) / 128, HID, 0, stream>>>(B1, gid, pooled, N, HID);
    head_kernel<<<G, HID, 0, stream>>>(pooled, Wc, bc, out, HID, C);
}

// Round 6
// 1369.842 us; speedup vs baseline: 1.3954x; 1.1193x over previous
//
#include <hip/hip_runtime.h>
#include <hip/hip_bf16.h>

// ---------------------------------------------------------------------------
// TAGConv (K=2) x2 + segment-max pool + linear head. bf16 intermediates,
// fp32 accumulate. Layer-2 commuted: z2@W2 = X1@W2a + P(X1@W2b + P(X1@W2c)).
// Round 6: layer-2 props gather INT8 row-quantized sources (per-row scale
// folded into the norm multiplier) -> 256B/row instead of 512B. The props
// are byte-service-bound (r5: 221us, FETCH 777MB, VALU 45%, BW 48%).
// ---------------------------------------------------------------------------

typedef unsigned short u16;
typedef unsigned int u32;

__device__ inline float u2f(u16 u) { return __uint_as_float(((u32)u) << 16); }
__device__ inline u16 f2u(float f) {
    __hip_bfloat16 b = __float2bfloat16(f);
    return *reinterpret_cast<u16*>(&b);
}

// ---------------------------- CSR build ------------------------------------
// hist/fill: 8 dst-windows; group w = blockIdx&7 owns window w and scans the
// whole edge list (grid-stride). Under round-robin block->XCD dispatch all
// stores to a window come from one XCD => L2-resident, one writeback.

__global__ __launch_bounds__(256) void hist_kernel(
    const int* __restrict__ dst, int* __restrict__ deg, int E, int wstep) {
    int grp = blockIdx.x & 7;
    int vb  = blockIdx.x >> 3;
    int nvb = gridDim.x >> 3;
    int lo = grp * wstep, hi = lo + wstep;
    int stride = nvb * 256;
    for (int i = vb * 256 + threadIdx.x; i < E; i += stride) {
        int d = dst[i];
        if (d >= lo && d < hi) atomicAdd(&deg[d], 1);
    }
}

__global__ __launch_bounds__(256) void fill_kernel(
    const int* __restrict__ src, const int* __restrict__ dst,
    int* __restrict__ cursor, int* __restrict__ colidx, int E, int wstep) {
    int grp = blockIdx.x & 7;
    int vb  = blockIdx.x >> 3;
    int nvb = gridDim.x >> 3;
    int lo = grp * wstep, hi = lo + wstep;
    int stride = nvb * 256;
    for (int i = vb * 256 + threadIdx.x; i < E; i += stride) {
        int d = dst[i];
        if (d >= lo && d < hi) {
            int pos = atomicAdd(&cursor[d], 1);
            colidx[pos] = src[i];
        }
    }
}

__global__ void norm_kernel(const int* __restrict__ deg, float* __restrict__ normv, int N) {
    int i = blockIdx.x * blockDim.x + threadIdx.x;
    if (i < N) {
        int d = deg[i];
        float fd = d < 1 ? 1.0f : (float)d;
        normv[i] = rsqrtf(fd);
    }
}

// Multi-block scan: scan1 (per-1024-chunk local excl scan + block sums),
// scan2 (single block excl scan of sums), scan3 (add offsets, write cursor).
__global__ void scan1_kernel(const int* __restrict__ deg, int* __restrict__ rowptr,
                             int* __restrict__ bsum, int n) {
    __shared__ int sd[1024];
    int t = threadIdx.x;
    int i = blockIdx.x * 1024 + t;
    int v = (i < n) ? deg[i] : 0;
    sd[t] = v;
    __syncthreads();
    for (int off = 1; off < 1024; off <<= 1) {
        int x = (t >= off) ? sd[t - off] : 0;
        __syncthreads();
        sd[t] += x;
        __syncthreads();
    }
    if (i < n) rowptr[i] = sd[t] - v;
    if (t == 1023) bsum[blockIdx.x] = sd[t];
}

__global__ void scan2_kernel(int* __restrict__ bsum, int nb) {
    __shared__ int sd[1024];
    int t = threadIdx.x;
    int v = (t < nb) ? bsum[t] : 0;
    sd[t] = v;
    __syncthreads();
    for (int off = 1; off < 1024; off <<= 1) {
        int x = (t >= off) ? sd[t - off] : 0;
        __syncthreads();
        sd[t] += x;
        __syncthreads();
    }
    if (t < nb) bsum[t] = sd[t] - v;
}

__global__ void scan3_kernel(int* __restrict__ rowptr, int* __restrict__ cursor,
                             const int* __restrict__ bsum, int n, int E) {
    int i = blockIdx.x * blockDim.x + threadIdx.x;
    if (i < n) {
        int r = rowptr[i] + bsum[i >> 10];
        rowptr[i] = r;
        cursor[i] = r;
    }
    if (i == 0) rowptr[n] = E;
}

// ------------------------------ cast h -------------------------------------

struct alignas(4) U2 { u16 v[2]; };
struct alignas(8) U4 { u16 v[4]; };
template <int VPT> struct VT;
template <> struct VT<2> { using T = U2; };
template <> struct VT<4> { using T = U4; };

// CAT1[:, 0:IN] = bf16(h), 4 floats per thread
__global__ void cast_kernel(const float* __restrict__ h, u16* __restrict__ cat,
                            int ngroups, int in4, int ldcat) {
    int i = blockIdx.x * blockDim.x + threadIdx.x;
    if (i < ngroups) {
        int r = i / in4, c4 = i % in4;
        float4 f = *(const float4*)(h + (size_t)i * 4);
        U4 o;
        o.v[0] = f2u(f.x); o.v[1] = f2u(f.y); o.v[2] = f2u(f.z); o.v[3] = f2u(f.w);
        *(U4*)(cat + (size_t)r * ldcat + c4 * 4) = o;
    }
}

// ----------------------------- propagation (bf16) --------------------------
// out[i,:] = norm[i] * sum_{e in row i} norm[col_e] * in[col_e,:]
// One wave per node (4 nodes/block). Lane holds VPT features (vector load).
// Edge loop unrolled x8 for memory-level parallelism.

template <int VPT>
__global__ __launch_bounds__(256) void prop_kernel(
    const u16* __restrict__ in, int ldin,
    u16* __restrict__ out, int ldout,
    const int* __restrict__ rowptr, const int* __restrict__ colidx,
    const float* __restrict__ normv, int N) {
    using V = typename VT<VPT>::T;
    int node = blockIdx.x * 4 + (threadIdx.x >> 6);
    if (node >= N) return;
    int lane = threadIdx.x & 63;
    const u16* ip = in + lane * VPT;
    int s = rowptr[node], e = rowptr[node + 1];
    float acc[VPT];
    #pragma unroll
    for (int q = 0; q < VPT; ++q) acc[q] = 0.f;
    int p = s;
    for (; p + 8 <= e; p += 8) {
        int c[8];
        #pragma unroll
        for (int j = 0; j < 8; ++j) c[j] = colidx[p + j];
        V v[8];
        #pragma unroll
        for (int j = 0; j < 8; ++j) v[j] = *(const V*)(ip + (size_t)c[j] * ldin);
        float nm[8];
        #pragma unroll
        for (int j = 0; j < 8; ++j) nm[j] = normv[c[j]];
        #pragma unroll
        for (int j = 0; j < 8; ++j)
            #pragma unroll
            for (int q = 0; q < VPT; ++q)
                acc[q] += nm[j] * u2f(v[j].v[q]);
    }
    for (; p < e; ++p) {
        int c = colidx[p];
        float nm = normv[c];
        V v = *(const V*)(ip + (size_t)c * ldin);
        #pragma unroll
        for (int q = 0; q < VPT; ++q) acc[q] += nm * u2f(v.v[q]);
    }
    float nn = normv[node];
    V o;
    #pragma unroll
    for (int q = 0; q < VPT; ++q) o.v[q] = f2u(nn * acc[q]);
    *(V*)(out + (size_t)node * ldout + lane * VPT) = o;
}

// ----------------------- int8 row-quantized prop (d=256) -------------------
// quant: q[i,:] = round(x[i,:] * 127/rowmax), m[i] = norm[i] * rowmax/127.
// prop_q8: out[i,:] = norm[i] * sum_e m[col_e] * q[col_e,:]   (256B/row read)

__global__ __launch_bounds__(256) void quant_kernel(
    const u16* __restrict__ x, const float* __restrict__ normv,
    signed char* __restrict__ q, float* __restrict__ m, int N) {
    int row = blockIdx.x * 4 + (threadIdx.x >> 6);
    if (row >= N) return;
    int lane = threadIdx.x & 63;
    U4 v = *(const U4*)(x + (size_t)row * 256 + lane * 4);
    float f[4];
    #pragma unroll
    for (int i = 0; i < 4; ++i) f[i] = u2f(v.v[i]);
    float mx = fmaxf(fmaxf(fabsf(f[0]), fabsf(f[1])),
                     fmaxf(fabsf(f[2]), fabsf(f[3])));
    #pragma unroll
    for (int off = 32; off > 0; off >>= 1)
        mx = fmaxf(mx, __shfl_xor(mx, off, 64));
    float inv = mx > 0.f ? 127.f / mx : 0.f;
    char4 o;
    o.x = (signed char)(int)rintf(f[0] * inv);
    o.y = (signed char)(int)rintf(f[1] * inv);
    o.z = (signed char)(int)rintf(f[2] * inv);
    o.w = (signed char)(int)rintf(f[3] * inv);
    *(char4*)(q + (size_t)row * 256 + lane * 4) = o;
    if (lane == 0) m[row] = normv[row] * (mx * (1.f / 127.f));
}

__global__ __launch_bounds__(256) void prop_q8_kernel(
    const signed char* __restrict__ qin, const float* __restrict__ m,
    u16* __restrict__ out,
    const int* __restrict__ rowptr, const int* __restrict__ colidx,
    const float* __restrict__ normv, int N) {
    int node = blockIdx.x * 4 + (threadIdx.x >> 6);
    if (node >= N) return;
    int lane = threadIdx.x & 63;
    const signed char* ip = qin + lane * 4;
    int s = rowptr[node], e = rowptr[node + 1];
    float a0 = 0.f, a1 = 0.f, a2 = 0.f, a3 = 0.f;
    int p = s;
    for (; p + 8 <= e; p += 8) {
        int c[8];
        #pragma unroll
        for (int j = 0; j < 8; ++j) c[j] = colidx[p + j];
        int w[8];
        #pragma unroll
        for (int j = 0; j < 8; ++j) w[j] = *(const int*)(ip + (size_t)c[j] * 256);
        float nm[8];
        #pragma unroll
        for (int j = 0; j < 8; ++j) nm[j] = m[c[j]];
        #pragma unroll
        for (int j = 0; j < 8; ++j) {
            a0 += nm[j] * (float)(signed char)(w[j]);
            a1 += nm[j] * (float)(signed char)(w[j] >> 8);
            a2 += nm[j] * (float)(signed char)(w[j] >> 16);
            a3 += nm[j] * (float)(w[j] >> 24);
        }
    }
    for (; p < e; ++p) {
        int c = colidx[p];
        int w = *(const int*)(ip + (size_t)c * 256);
        float nm = m[c];
        a0 += nm * (float)(signed char)(w);
        a1 += nm * (float)(signed char)(w >> 8);
        a2 += nm * (float)(signed char)(w >> 16);
        a3 += nm * (float)(w >> 24);
    }
    float nn = normv[node];
    U4 o;
    o.v[0] = f2u(nn * a0);
    o.v[1] = f2u(nn * a1);
    o.v[2] = f2u(nn * a2);
    o.v[3] = f2u(nn * a3);
    *(U4*)(out + (size_t)node * 256 + lane * 4) = o;
}

// ------------------------------- MFMA GEMM ---------------------------------
// Cout[M x 256] = [relu]( A(bf16,[Mpad x lda]) @ Bt^T [+Cadd] [+bias] ) -> bf16
// Bt is [256 x K] bf16 row-major (pre-transposed weights, k-contiguous).
// Tile 128x64, BK=32, 4 waves (2x2), wave = 4x2 grid of 16x16x32 MFMAs.
// B panel (64 x K <= 48 KB) resident in LDS; A tile double-buffered via
// global_load_lds width-16.

typedef __attribute__((ext_vector_type(8))) short bf16x8f;
typedef __attribute__((ext_vector_type(4))) float f32x4;

__device__ inline void async16(const void* g, void* l) {
    __builtin_amdgcn_global_load_lds(
        (__attribute__((address_space(1))) void*)(g),
        (__attribute__((address_space(3))) void*)(l), 16, 0, 0);
}

constexpr int GBM = 128, GBN = 64, GBK = 32, KMAX = 384;

__device__ inline void stageA(const u16* __restrict__ A, int lda, int row0, int k0,
                              u16* dst, int tid) {
    // 128 rows x 32 bf16 cols = 8 KB = 512 x 16B chunks; 256 threads x 2.
    #pragma unroll
    for (int i = 0; i < 2; ++i) {
        int c = tid + i * 256;
        int row = c >> 2, seg = c & 3;
        async16(A + (size_t)(row0 + row) * lda + k0 + seg * 8, dst + c * 8);
    }
}

__global__ __launch_bounds__(256) void gemm_mfma(
    const u16* __restrict__ A, int lda,
    const u16* __restrict__ Bt,          // [256 x K]
    const u16* __restrict__ Cadd,        // nullable, [Mpad x 256]
    const float* __restrict__ bias,      // nullable, [256]
    u16* __restrict__ Cout,              // [Mpad x 256]
    int M, int K, int relu) {
    __shared__ u16 Ab[2][GBM * GBK];
    __shared__ u16 Bs[GBN * KMAX];
    const int tid = threadIdx.x;
    const int lane = tid & 63;
    const int wave = tid >> 6;
    const int wm = wave >> 1, wn = wave & 1;
    const int row0 = blockIdx.x * GBM;
    const int col0 = blockIdx.y * GBN;
    const int NOUT = 256;

    // stage B panel: contiguous 64*K bf16 from Bt + col0*K
    {
        const u16* src = Bt + (size_t)col0 * K;
        int chunks = GBN * K / 8;
        for (int c = tid; c < chunks; c += 256) async16(src + c * 8, &Bs[c * 8]);
    }
    stageA(A, lda, row0, 0, Ab[0], tid);
    __syncthreads();

    f32x4 acc[4][2];
    #pragma unroll
    for (int mi = 0; mi < 4; ++mi)
        #pragma unroll
        for (int ni = 0; ni < 2; ++ni) acc[mi][ni] = (f32x4)0.f;

    const int nk = K / GBK;
    const int mb = lane & 15;
    const int kk = (lane >> 4) * 8;
    for (int ks = 0; ks < nk; ++ks) {
        int cur = ks & 1;
        if (ks + 1 < nk) stageA(A, lda, row0, (ks + 1) * GBK, Ab[cur ^ 1], tid);
        bf16x8f a[4], b[2];
        #pragma unroll
        for (int mi = 0; mi < 4; ++mi)
            a[mi] = *(const bf16x8f*)&Ab[cur][(wm * 64 + mi * 16 + mb) * GBK + kk];
        #pragma unroll
        for (int ni = 0; ni < 2; ++ni)
            b[ni] = *(const bf16x8f*)&Bs[(size_t)(wn * 32 + ni * 16 + mb) * K + ks * GBK + kk];
        #pragma unroll
        for (int mi = 0; mi < 4; ++mi)
            #pragma unroll
            for (int ni = 0; ni < 2; ++ni)
                acc[mi][ni] = __builtin_amdgcn_mfma_f32_16x16x32_bf16(
                    a[mi], b[ni], acc[mi][ni], 0, 0, 0);
        __syncthreads();
    }

    // epilogue: C/D layout col = lane&15, row = (lane>>4)*4 + r
    #pragma unroll
    for (int mi = 0; mi < 4; ++mi) {
        #pragma unroll
        for (int r = 0; r < 4; ++r) {
            int row = row0 + wm * 64 + mi * 16 + (lane >> 4) * 4 + r;
            if (row < M) {
                #pragma unroll
                for (int ni = 0; ni < 2; ++ni) {
                    int col = col0 + wn * 32 + ni * 16 + (lane & 15);
                    float v = acc[mi][ni][r];
                    if (Cadd) v += u2f(Cadd[(size_t)row * NOUT + col]);
                    if (bias) v += bias[col];
                    if (relu) v = fmaxf(v, 0.f);
                    Cout[(size_t)row * NOUT + col] = f2u(v);
                }
            }
        }
    }
}

// Wt[n*K + k] = bf16(W[k*Nn + n])
__global__ void transpose_cast(const float* __restrict__ W, u16* __restrict__ Wt,
                               int K, int Nn) {
    int idx = blockIdx.x * blockDim.x + threadIdx.x;
    if (idx < K * Nn) {
        int n = idx / K, k = idx % K;
        Wt[idx] = f2u(W[(size_t)k * Nn + n]);
    }
}

// ------------------------------ pool + head --------------------------------

__global__ void pool_kernel(const u16* __restrict__ x, const int* __restrict__ gid,
                            float* __restrict__ pooled, int N, int HID) {
    int t = threadIdx.x;
    int n0 = blockIdx.x * 128;
    int n1 = n0 + 128 < N ? n0 + 128 : N;
    float cur = 0.f;
    int cg = gid[n0];
    for (int n = n0; n < n1; ++n) {
        int g = gid[n];
        if (g != cg) {
            atomicMax((int*)&pooled[(size_t)cg * HID + t], __float_as_int(cur));
            cg = g;
            cur = 0.f;
        }
        float v = u2f(x[(size_t)n * HID + t]);
        cur = cur > v ? cur : v;
    }
    atomicMax((int*)&pooled[(size_t)cg * HID + t], __float_as_int(cur));
}

__global__ void head_kernel(const float* __restrict__ pooled, const float* __restrict__ Wc,
                            const float* __restrict__ bc, float* __restrict__ out,
                            int HID, int C) {
    __shared__ float row[256];
    int g = blockIdx.x;
    int t = threadIdx.x;
    if (t < HID) row[t] = pooled[(size_t)g * HID + t];
    __syncthreads();
    if (t < C) {
        float s = bc[t];
        for (int k = 0; k < HID; ++k) s += row[k] * Wc[(size_t)k * C + t];
        out[(size_t)g * C + t] = s;
    }
}

// ------------------------------- launch ------------------------------------

extern "C" void kernel_launch(void* const* d_in, const int* in_sizes, int n_in,
                              void* d_out, int out_size, void* d_ws, size_t ws_size,
                              hipStream_t stream) {
    const float* h  = (const float*)d_in[0];
    const int* src  = (const int*)d_in[1];
    const int* dst  = (const int*)d_in[2];
    const int* gid  = (const int*)d_in[3];
    const float* W1 = (const float*)d_in[4];
    const float* b1 = (const float*)d_in[5];
    const float* W2 = (const float*)d_in[6];
    const float* b2 = (const float*)d_in[7];
    const float* Wc = (const float*)d_in[8];
    const float* bc = (const float*)d_in[9];
    float* out = (float*)d_out;

    const int N   = in_sizes[3];          // 100000
    const int E   = in_sizes[1];          // 3200000
    const int IN  = in_sizes[0] / N;      // 128
    const int HID = in_sizes[5];          // 256
    const int C   = in_sizes[9];          // 10
    const int G   = out_size / C;         // 64
    const int CAT = 3 * IN;               // 384
    const int Mpad = (N + 127) & ~127;    // 100096 (multiple of GBM)

    char* wp = (char*)d_ws;
    auto alloc = [&](size_t bytes) {
        char* p = wp;
        wp += (bytes + 255) & ~(size_t)255;
        return p;
    };
    float* pooled = (float*)alloc((size_t)G * HID * sizeof(float));
    float* normv  = (float*)alloc((size_t)N * sizeof(float));
    int* deg      = (int*)alloc((size_t)N * sizeof(int));
    int* rowptr   = (int*)alloc((size_t)(N + 1) * sizeof(int));
    int* cursor   = (int*)alloc((size_t)N * sizeof(int));
    int* bsum     = (int*)alloc(1024 * sizeof(int));
    int* colidx   = (int*)alloc((size_t)E * sizeof(int));
    u16* Wt1      = (u16*)alloc((size_t)CAT * HID * sizeof(u16));        // [256 x 384]
    u16* Wt2      = (u16*)alloc((size_t)3 * HID * HID * sizeof(u16));    // 3 x [256 x 256]
    u16* CAT1     = (u16*)alloc((size_t)Mpad * CAT * sizeof(u16));       // [h|Ph|P2h]
    u16* X1       = (u16*)alloc((size_t)Mpad * HID * sizeof(u16));
    u16* B2       = (u16*)alloc((size_t)Mpad * HID * sizeof(u16));
    u16* B1       = CAT1;                              // alias: CAT1 dead after GEMM1
    signed char* Q8 = (signed char*)(CAT1 + (size_t)Mpad * HID);  // CAT1 tail (25.6MB)
    float* mv     = (float*)cursor;                    // cursor dead after fill

    // --- norm + CSR build (XCD-ownership windows: 8 windows over dst) ---
    const int wstep = (N + 7) / 8;        // 12500
    hipMemsetAsync(deg, 0, (size_t)N * sizeof(int), stream);
    hist_kernel<<<8 * 512, 256, 0, stream>>>(dst, deg, E, wstep);
    norm_kernel<<<(N + 255) / 256, 256, 0, stream>>>(deg, normv, N);
    int nb = (N + 1023) / 1024;
    scan1_kernel<<<nb, 1024, 0, stream>>>(deg, rowptr, bsum, N);
    scan2_kernel<<<1, 1024, 0, stream>>>(bsum, nb);
    scan3_kernel<<<(N + 255) / 256, 256, 0, stream>>>(rowptr, cursor, bsum, N, E);
    fill_kernel<<<8 * 512, 256, 0, stream>>>(src, dst, cursor, colidx, E, wstep);

    // --- weight transpose + bf16 cast (small) ---
    transpose_cast<<<(CAT * HID + 255) / 256, 256, 0, stream>>>(W1, Wt1, CAT, HID);
    for (int s2 = 0; s2 < 3; ++s2)
        transpose_cast<<<(HID * HID + 255) / 256, 256, 0, stream>>>(
            W2 + (size_t)s2 * HID * HID, Wt2 + (size_t)s2 * HID * HID, HID, HID);

    // --- layer 1: CAT1 = [bf16(h) | P h | P^2 h]; X1 = relu(CAT1@W1+b1) ---
    {
        int ngroups = N * (IN / 4);
        cast_kernel<<<(ngroups + 255) / 256, 256, 0, stream>>>(h, CAT1, ngroups, IN / 4, CAT);
    }
    prop_kernel<2><<<(N + 3) / 4, 256, 0, stream>>>(CAT1, CAT, CAT1 + IN, CAT,
                                                    rowptr, colidx, normv, N);
    prop_kernel<2><<<(N + 3) / 4, 256, 0, stream>>>(CAT1 + IN, CAT, CAT1 + 2 * IN, CAT,
                                                    rowptr, colidx, normv, N);
    dim3 ggrid(Mpad / GBM, HID / GBN);
    gemm_mfma<<<ggrid, 256, 0, stream>>>(CAT1, CAT, Wt1, nullptr, b1, X1, N, CAT, 1);

    // --- layer 2 (commuted): X2 = relu(X1@W2a + P(X1@W2b + P(X1@W2c)) + b2) ---
    gemm_mfma<<<ggrid, 256, 0, stream>>>(X1, HID, Wt2 + (size_t)2 * HID * HID,
                                         nullptr, nullptr, B1, N, HID, 0);
    quant_kernel<<<(N + 3) / 4, 256, 0, stream>>>(B1, normv, Q8, mv, N);
    prop_q8_kernel<<<(N + 3) / 4, 256, 0, stream>>>(Q8, mv, B2, rowptr, colidx, normv, N);
    gemm_mfma<<<ggrid, 256, 0, stream>>>(X1, HID, Wt2 + (size_t)HID * HID,
                                         B2, nullptr, B1, N, HID, 0);
    quant_kernel<<<(N + 3) / 4, 256, 0, stream>>>(B1, normv, Q8, mv, N);
    prop_q8_kernel<<<(N + 3) / 4, 256, 0, stream>>>(Q8, mv, B2, rowptr, colidx, normv, N);
    gemm_mfma<<<ggrid, 256, 0, stream>>>(X1, HID, Wt2, B2, b2, B1, N, HID, 1);

    // --- pool + head ---
    hipMemsetAsync(pooled, 0, (size_t)G * HID * sizeof(float), stream);
    pool_kernel<<<(N + 127) / 128, HID, 0, stream>>>(B1, gid, pooled, N, HID);
    head_kernel<<<G, HID, 0, stream>>>(pooled, Wc, bc, out, HID, C);
}